// Round 1
// 1081.610 us; speedup vs baseline: 1.0332x; 1.0332x over previous
//
#include <hip/hip_runtime.h>
#include <hip/hip_bf16.h>
#include <math.h>

constexpr int kB   = 64;
constexpr int kT   = 77;
constexpr int kD   = 256;
constexpr int kH   = 8;
constexpr int kDH  = 32;
constexpr int kDFF = 2048;
constexpr int kM1  = 400;
constexpr int kMKV = 800;
constexpr float kEPS = 1e-5f;
constexpr float kNEG = -1000000000.0f;

typedef __attribute__((ext_vector_type(8))) short short8;
typedef __attribute__((ext_vector_type(4))) float floatx4;

// RNE fp32 -> bf16 pair, packed into one uint (low = x, high = y)
__device__ __forceinline__ unsigned pkbf(float x, float y) {
    unsigned ux = __float_as_uint(x), uy = __float_as_uint(y);
    ux = (ux + 0x7fffu + ((ux >> 16) & 1u)) >> 16;
    uy = (uy + 0x7fffu + ((uy >> 16) & 1u)) & 0xffff0000u;
    return ux | uy;
}

// ---------------------------------------------------------------------------
// MFMA bf16 GEMM: C[b] = A[b] @ W[sid[b]]^T + bias[sid[b]]  (opt. ReLU)
// A rows < splitM from A1, >= splitM from A2 (for the CA-KV concat).
// Tile 128x128xBK64; 256 threads = 4 waves in 2x2, each wave does 64x64 via
// 4x4 mfma_f32_16x16x32_bf16. LDS tiles: [128][88] ushort (176B row stride:
// 16B-aligned for ds_read_b128, bank pattern 12m%32 -> 2-way only = free).
// Grid.x = tilesN*tilesM flattened y-fastest: consecutive blocks share W tile.
// ---------------------------------------------------------------------------
__global__ __launch_bounds__(256) void mfma_gemm(
    const float* __restrict__ A1, long long sA1,
    const float* __restrict__ A2, long long sA2, int splitM, int lda,
    const float* __restrict__ W, long long sW, int ldw,
    const float* __restrict__ bias, long long sB,
    float* __restrict__ C, long long sC, int ldc,
    const int* __restrict__ sid, int M, int N, int K, int tilesM, int relu)
{
    __shared__ unsigned short As[128][88];
    __shared__ unsigned short Bs[128][88];

    int b = blockIdx.z;
    int s = sid[b];
    int ty = blockIdx.x % tilesM;          // row tile (fastest -> W-tile reuse)
    int tx = blockIdx.x / tilesM;          // col tile
    int tm0 = ty * 128, tn0 = tx * 128;

    const float* Wb = W + (long long)s * sW;
    const float* Bb = bias + (long long)s * sB;
    float* Cb = C + (long long)b * sC;

    int t = threadIdx.x;
    int lane = t & 63, wv = t >> 6;
    int wm = wv >> 1, wn = wv & 1;
    int q = lane >> 4, mrow = lane & 15;

    floatx4 acc[4][4] = {};

    for (int k0 = 0; k0 < K; k0 += 64) {
        // Stage A (128x64 fp32 -> bf16). 16 lanes x float4 per row, coalesced.
        #pragma unroll
        for (int p = 0; p < 8; p++) {
            int row = (t >> 4) + 16 * p;
            int kf  = (t & 15) * 4;
            int ar = tm0 + row;
            float4 v = make_float4(0.f, 0.f, 0.f, 0.f);
            if (ar < M) {
                const float* src = (ar < splitM)
                    ? (A1 + (long long)b * sA1 + (long long)ar * lda)
                    : (A2 + (long long)b * sA2 + (long long)(ar - splitM) * lda);
                v = *(const float4*)(src + k0 + kf);
            }
            *(uint2*)&As[row][kf] = make_uint2(pkbf(v.x, v.y), pkbf(v.z, v.w));
        }
        // Stage B (W rows tn0..tn0+127; N is always a multiple of 128)
        #pragma unroll
        for (int p = 0; p < 8; p++) {
            int row = (t >> 4) + 16 * p;
            int kf  = (t & 15) * 4;
            const float* src = Wb + (long long)(tn0 + row) * ldw + k0 + kf;
            float4 v = *(const float4*)src;
            *(uint2*)&Bs[row][kf] = make_uint2(pkbf(v.x, v.y), pkbf(v.z, v.w));
        }
        __syncthreads();

        #pragma unroll
        for (int ks = 0; ks < 2; ks++) {
            int kk = ks * 32 + q * 8;   // A[m][k]: m=lane&15, k=quad*8+j
            short8 af[4], bfr[4];
            #pragma unroll
            for (int i = 0; i < 4; i++) {
                af[i]  = *(const short8*)&As[wm * 64 + i * 16 + mrow][kk];
                bfr[i] = *(const short8*)&Bs[wn * 64 + i * 16 + mrow][kk];
            }
            #pragma unroll
            for (int mi = 0; mi < 4; mi++)
                #pragma unroll
                for (int ni = 0; ni < 4; ni++)
                    acc[mi][ni] = __builtin_amdgcn_mfma_f32_16x16x32_bf16(
                        af[mi], bfr[ni], acc[mi][ni], 0, 0, 0);
        }
        __syncthreads();
    }

    // Epilogue: C/D layout col=lane&15, row=(lane>>4)*4+reg
    #pragma unroll
    for (int ni = 0; ni < 4; ni++) {
        int cgl = tn0 + wn * 64 + ni * 16 + mrow;
        float bv = Bb[cgl];
        #pragma unroll
        for (int mi = 0; mi < 4; mi++) {
            #pragma unroll
            for (int e = 0; e < 4; e++) {
                int r = tm0 + wm * 64 + mi * 16 + q * 4 + e;
                if (r < M) {
                    float o = acc[mi][ni][e] + bv;
                    if (relu) o = fmaxf(o, 0.f);
                    Cb[(long long)r * ldc + cgl] = o;
                }
            }
        }
    }
}

// ---------------------------------------------------------------------------
// Attention v3: block per (b, h, 32-q-row tile). 256 threads.
// K/V/mask staged in LDS (coalesced), Q rows in registers, online softmax.
// Thread (qg=t>>4 -> rows 2qg,2qg+1; jl=t&15). Phase A computes 2x4 scores
// per thread IN REGISTERS; the 16 lanes sharing qg hold the full 64-wide row
// (j = jl+16*jj), so row max/sum are 4-level __shfl_xor reductions within the
// 16-lane group — no serial stats phase, no m/l/alpha LDS arrays, and S is
// written already exponentiated. 3 barriers/tile (was 4).
// Phase B: thread -> rows 2qg,2qg+1 x d=2*jl..+1.
// ---------------------------------------------------------------------------
__global__ __launch_bounds__(256) void attn2(
    const float* __restrict__ Q, long long sQ, int ldq,
    const float* __restrict__ Kp, long long sK, int ldk,
    const float* __restrict__ Vp, long long sV, int ldv,
    const unsigned char* __restrict__ m1, int sM1,
    const unsigned char* __restrict__ m2, int sM2,
    int split, int nk, int ntiles,
    float* __restrict__ O, long long sO, int ldo, float scale)
{
    __shared__ float Ks[64][36];
    __shared__ float Vs[64][36];
    __shared__ float S[32][68];
    __shared__ float mk[64];

    int t = threadIdx.x;
    int qt = blockIdx.x, h = blockIdx.y, b = blockIdx.z;
    int qbase = qt * 32;

    const float* Qb = Q + (long long)b * sQ + h * kDH;
    const float* Kb = Kp + (long long)b * sK + h * kDH;
    const float* Vb = Vp + (long long)b * sV + h * kDH;

    int qg = t >> 4, jl = t & 15;
    int r0 = 2 * qg, r1 = r0 + 1;
    int gq0 = qbase + r0, gq1 = qbase + r1;

    float4 qa0[8], qa1[8];
    #pragma unroll
    for (int i = 0; i < 8; i++) {
        qa0[i] = (gq0 < kT) ? *(const float4*)(Qb + (long long)gq0 * ldq + i * 4)
                            : make_float4(0.f, 0.f, 0.f, 0.f);
        qa1[i] = (gq1 < kT) ? *(const float4*)(Qb + (long long)gq1 * ldq + i * 4)
                            : make_float4(0.f, 0.f, 0.f, 0.f);
    }
    float oa00 = 0.f, oa01 = 0.f, oa10 = 0.f, oa11 = 0.f;
    // Online-softmax state, replicated across the 16 lanes of each qg group
    float m0 = -INFINITY, m1r = -INFINITY, l0 = 0.f, l1 = 0.f;

    for (int tile = 0; tile < ntiles; tile++) {
        int jt0 = tile * 64;
        __syncthreads();   // previous phase B done before restaging

        // Stage K/V tile (64x32 each), coalesced float4
        #pragma unroll
        for (int p = 0; p < 2; p++) {
            int id = t + 256 * p;
            int j = id >> 3, dq = (id & 7) * 4;
            int gj = jt0 + j;
            float4 kv = (gj < nk) ? *(const float4*)(Kb + (long long)gj * ldk + dq)
                                  : make_float4(0.f, 0.f, 0.f, 0.f);
            float4 vv = (gj < nk) ? *(const float4*)(Vb + (long long)gj * ldv + dq)
                                  : make_float4(0.f, 0.f, 0.f, 0.f);
            *(float4*)&Ks[j][dq] = kv;
            *(float4*)&Vs[j][dq] = vv;
        }
        if (t < 64) {
            int gj = jt0 + t;
            float m = 0.f;
            if (gj < nk)
                m = ((gj < split) ? m1[b * sM1 + gj] : m2[b * sM2 + (gj - split)]) ? 1.f : 0.f;
            mk[t] = m;
        }
        __syncthreads();

        // Phase A: scores in registers
        float s0[4], s1[4];
        #pragma unroll
        for (int jj = 0; jj < 4; jj++) {
            int j = jl + 16 * jj;
            float a0 = 0.f, a1 = 0.f;
            #pragma unroll
            for (int d4 = 0; d4 < 8; d4++) {
                float4 kv = *(const float4*)&Ks[j][d4 * 4];
                a0 += qa0[d4].x * kv.x + qa0[d4].y * kv.y + qa0[d4].z * kv.z + qa0[d4].w * kv.w;
                a1 += qa1[d4].x * kv.x + qa1[d4].y * kv.y + qa1[d4].z * kv.z + qa1[d4].w * kv.w;
            }
            int gj = jt0 + j;
            if (gj < nk) {
                float msk = mk[j];
                s0[jj] = (msk != 0.f) ? kNEG : a0 * scale;
                s1[jj] = (msk != 0.f) ? kNEG : a1 * scale;
            } else {
                s0[jj] = -INFINITY; s1[jj] = -INFINITY;
            }
        }

        // Row max via 16-lane-group butterfly (each group holds the full row)
        float mt0 = fmaxf(fmaxf(s0[0], s0[1]), fmaxf(s0[2], s0[3]));
        float mt1 = fmaxf(fmaxf(s1[0], s1[1]), fmaxf(s1[2], s1[3]));
        #pragma unroll
        for (int off = 8; off >= 1; off >>= 1) {
            mt0 = fmaxf(mt0, __shfl_xor(mt0, off));
            mt1 = fmaxf(mt1, __shfl_xor(mt1, off));
        }
        float mn0 = fmaxf(m0, mt0), mn1 = fmaxf(m1r, mt1);
        float al0 = __expf(m0 - mn0);    // exp(-inf)=0 on first tile
        float al1 = __expf(m1r - mn1);

        // exp + write P to LDS + row sum
        float sum0 = 0.f, sum1 = 0.f;
        #pragma unroll
        for (int jj = 0; jj < 4; jj++) {
            int j = jl + 16 * jj;
            float p0 = __expf(s0[jj] - mn0);
            float p1 = __expf(s1[jj] - mn1);
            S[r0][j] = p0;
            S[r1][j] = p1;
            sum0 += p0; sum1 += p1;
        }
        #pragma unroll
        for (int off = 8; off >= 1; off >>= 1) {
            sum0 += __shfl_xor(sum0, off);
            sum1 += __shfl_xor(sum1, off);
        }
        l0 = l0 * al0 + sum0;
        l1 = l1 * al1 + sum1;
        m0 = mn0; m1r = mn1;
        __syncthreads();

        // Phase B: O += P @ V with rescale (alpha from registers)
        oa00 *= al0; oa01 *= al0; oa10 *= al1; oa11 *= al1;
        #pragma unroll
        for (int j4 = 0; j4 < 64; j4 += 4) {
            float4 p0 = *(const float4*)&S[r0][j4];
            float4 p1 = *(const float4*)&S[r1][j4];
            const float* p0a = (const float*)&p0;
            const float* p1a = (const float*)&p1;
            #pragma unroll
            for (int e = 0; e < 4; e++) {
                float2 v = *(const float2*)&Vs[j4 + e][2 * jl];
                oa00 += p0a[e] * v.x; oa01 += p0a[e] * v.y;
                oa10 += p1a[e] * v.x; oa11 += p1a[e] * v.y;
            }
        }
    }

    float li0 = 1.f / l0;
    float li1 = 1.f / l1;
    if (gq0 < kT) {
        float2 o = make_float2(oa00 * li0, oa01 * li0);
        *(float2*)(O + (long long)b * sO + (long long)gq0 * ldo + h * kDH + 2 * jl) = o;
    }
    if (gq1 < kT) {
        float2 o = make_float2(oa10 * li1, oa11 * li1);
        *(float2*)(O + (long long)b * sO + (long long)gq1 * ldo + h * kDH + 2 * jl) = o;
    }
}

// ---------------------------------------------------------------------------
// Fused residual-add + LayerNorm over D=256. Block = 256 threads = one row.
// ---------------------------------------------------------------------------
__global__ __launch_bounds__(256) void addln_kernel(
    const float* __restrict__ A, const float* __restrict__ R,
    const float* __restrict__ w, const float* __restrict__ bb,
    const int* __restrict__ sid, float* __restrict__ O)
{
    int t = blockIdx.x, b = blockIdx.y, d = threadIdx.x;
    long long base = ((long long)(b * kT + t)) * kD;
    float x = A[base + d] + R[base + d];

    __shared__ float r1[4], r2[4];
    int wid = d >> 6;

    float sacc = x;
    #pragma unroll
    for (int off = 32; off >= 1; off >>= 1) sacc += __shfl_xor(sacc, off);
    if ((d & 63) == 0) r1[wid] = sacc;
    __syncthreads();
    float mean = (r1[0] + r1[1] + r1[2] + r1[3]) * (1.0f / 256.0f);

    float diff = x - mean;
    float s2 = diff * diff;
    #pragma unroll
    for (int off = 32; off >= 1; off >>= 1) s2 += __shfl_xor(s2, off);
    if ((d & 63) == 0) r2[wid] = s2;
    __syncthreads();
    float var = (r2[0] + r2[1] + r2[2] + r2[3]) * (1.0f / 256.0f);

    int s = sid[b];
    float y = diff * rsqrtf(var + kEPS) * w[s * kD + d] + bb[s * kD + d];
    O[base + d] = y;
}

// ---------------------------------------------------------------------------
// Launch
// ---------------------------------------------------------------------------
extern "C" void kernel_launch(void* const* d_in, const int* in_sizes, int n_in,
                              void* d_out, int out_size, void* d_ws, size_t ws_size,
                              hipStream_t stream)
{
    const float*         text   = (const float*)d_in[0];
    const unsigned char* tmask  = (const unsigned char*)d_in[1];
    const float*         im1    = (const float*)d_in[2];
    const unsigned char* immk1  = (const unsigned char*)d_in[3];
    const float*         im2    = (const float*)d_in[4];
    const unsigned char* immk2  = (const unsigned char*)d_in[5];
    const int*           sid    = (const int*)d_in[6];
    const float* sa_in_w  = (const float*)d_in[7];
    const float* sa_in_b  = (const float*)d_in[8];
    const float* sa_out_w = (const float*)d_in[9];
    const float* sa_out_b = (const float*)d_in[10];
    const float* ca_in_w  = (const float*)d_in[11];
    const float* ca_in_b  = (const float*)d_in[12];
    const float* ca_out_w = (const float*)d_in[13];
    const float* ca_out_b = (const float*)d_in[14];
    const float* lin1_w   = (const float*)d_in[15];
    const float* lin1_b   = (const float*)d_in[16];
    const float* lin2_w   = (const float*)d_in[17];
    const float* lin2_b   = (const float*)d_in[18];
    const float* ln1_w    = (const float*)d_in[19];
    const float* ln1_b    = (const float*)d_in[20];
    const float* ln2_w    = (const float*)d_in[21];
    const float* ln2_b    = (const float*)d_in[22];
    const float* ln3_w    = (const float*)d_in[23];
    const float* ln3_b    = (const float*)d_in[24];
    float* out = (float*)d_out;

    // Workspace layout (floats)
    float* ws = (float*)d_ws;
    float* qkv_sa  = ws;                                   // B*T*768
    float* q_ca    = qkv_sa  + (long long)kB * kT * 768;   // B*T*256
    float* kv_ca   = q_ca    + (long long)kB * kT * kD;    // B*800*512
    float* attnbuf = kv_ca   + (long long)kB * kMKV * 512; // B*T*256
    float* tmp     = attnbuf + (long long)kB * kT * kD;    // B*T*256
    float* x1      = tmp     + (long long)kB * kT * kD;    // B*T*256
    float* x2      = x1      + (long long)kB * kT * kD;    // B*T*256
    float* hff     = x2      + (long long)kB * kT * kD;    // B*T*2048

    const float scale = 0.17677669529663687f;  // 1/sqrt(32)
    dim3 blk(256);

    auto gemm = [&](const float* A1, long long sA1, const float* A2, long long sA2,
                    int splitM, int lda,
                    const float* W, long long sW, int ldw,
                    const float* bias, long long sB,
                    float* C, long long sC, int ldc,
                    int M, int N, int K, int relu) {
        int tm = (M + 127) / 128, tn = N / 128;
        mfma_gemm<<<dim3(tm * tn, 1, kB), blk, 0, stream>>>(
            A1, sA1, A2, sA2, splitM, lda, W, sW, ldw, bias, sB,
            C, sC, ldc, sid, M, N, K, tm, relu);
    };

    // 1. SA QKV: (B,77,768)
    gemm(text, (long long)kT * kD, text, 0, kT, kD,
         sa_in_w, (long long)3 * kD * kD, kD, sa_in_b, 3 * kD,
         qkv_sa, (long long)kT * 768, 768, kT, 768, kD, 0);

    // 2. SA attention -> attnbuf
    attn2<<<dim3(3, kH, kB), blk, 0, stream>>>(
        qkv_sa,       (long long)kT * 768, 768,
        qkv_sa + 256, (long long)kT * 768, 768,
        qkv_sa + 512, (long long)kT * 768, 768,
        tmask, kT, tmask, kT, kT, kT, 2,
        attnbuf, (long long)kT * kD, kD, scale);

    // 3. SA out-proj -> tmp
    gemm(attnbuf, (long long)kT * kD, attnbuf, 0, kT, kD,
         sa_out_w, (long long)kD * kD, kD, sa_out_b, kD,
         tmp, (long long)kT * kD, kD, kT, kD, kD, 0);

    // 4. x1 = LN1(tmp + text)
    addln_kernel<<<dim3(kT, kB), blk, 0, stream>>>(tmp, text, ln1_w, ln1_b, sid, x1);

    // 5. CA Q (rows 0..255 of ca_in_w)
    gemm(x1, (long long)kT * kD, x1, 0, kT, kD,
         ca_in_w, (long long)3 * kD * kD, kD, ca_in_b, 3 * kD,
         q_ca, (long long)kT * kD, kD, kT, kD, kD, 0);

    // 6. CA KV: concat(im1,im2) @ [wk;wv]^T -> kv_ca (B,800,512), single launch
    gemm(im1, (long long)kM1 * kD, im2, (long long)kM1 * kD, kM1, kD,
         ca_in_w + (long long)kD * kD, (long long)3 * kD * kD, kD,
         ca_in_b + kD, 3 * kD,
         kv_ca, (long long)kMKV * 512, 512, kMKV, 512, kD, 0);

    // 7. CA attention -> attnbuf
    attn2<<<dim3(3, kH, kB), blk, 0, stream>>>(
        q_ca,        (long long)kT * kD, kD,
        kv_ca,       (long long)kMKV * 512, 512,
        kv_ca + 256, (long long)kMKV * 512, 512,
        immk1, kM1, immk2, kM1, kM1, kMKV, 13,
        attnbuf, (long long)kT * kD, kD, scale);

    // 8. CA out-proj -> tmp
    gemm(attnbuf, (long long)kT * kD, attnbuf, 0, kT, kD,
         ca_out_w, (long long)kD * kD, kD, ca_out_b, kD,
         tmp, (long long)kT * kD, kD, kT, kD, kD, 0);

    // 9. x2 = LN2(tmp + x1)
    addln_kernel<<<dim3(kT, kB), blk, 0, stream>>>(tmp, x1, ln2_w, ln2_b, sid, x2);

    // 10. FFN1: hff = relu(x2 @ lin1_w^T + lin1_b)
    gemm(x2, (long long)kT * kD, x2, 0, kT, kD,
         lin1_w, (long long)kDFF * kD, kD, lin1_b, kDFF,
         hff, (long long)kT * kDFF, kDFF, kT, kDFF, kD, 1);

    // 11. FFN2: tmp = hff @ lin2_w^T + lin2_b
    gemm(hff, (long long)kT * kDFF, hff, 0, kT, kDFF,
         lin2_w, (long long)kD * kDFF, kDFF, lin2_b, kD,
         tmp, (long long)kT * kD, kD, kT, kD, kDFF, 0);

    // 12. out = LN3(tmp + x2)
    addln_kernel<<<dim3(kT, kB), blk, 0, stream>>>(tmp, x2, ln3_w, ln3_b, sid, out);
}

// Round 2
// 1005.947 us; speedup vs baseline: 1.1109x; 1.0752x over previous
//
#include <hip/hip_runtime.h>
#include <hip/hip_bf16.h>
#include <math.h>

constexpr int kB   = 64;
constexpr int kT   = 77;
constexpr int kD   = 256;
constexpr int kH   = 8;
constexpr int kDH  = 32;
constexpr int kDFF = 2048;
constexpr int kM1  = 400;
constexpr int kMKV = 800;
constexpr float kEPS = 1e-5f;
constexpr float kNEG = -1000000000.0f;

typedef __attribute__((ext_vector_type(8))) short short8;
typedef __attribute__((ext_vector_type(4))) float floatx4;
typedef __attribute__((ext_vector_type(16))) float floatx16;

// RNE fp32 -> bf16 pair, packed into one uint (low = x, high = y)
__device__ __forceinline__ unsigned pkbf(float x, float y) {
    unsigned ux = __float_as_uint(x), uy = __float_as_uint(y);
    ux = (ux + 0x7fffu + ((ux >> 16) & 1u)) >> 16;
    uy = (uy + 0x7fffu + ((uy >> 16) & 1u)) & 0xffff0000u;
    return ux | uy;
}
__device__ __forceinline__ unsigned short bf16u(float x) {
    unsigned u = __float_as_uint(x);
    return (unsigned short)((u + 0x7fffu + ((u >> 16) & 1u)) >> 16);
}

// ---------------------------------------------------------------------------
// MFMA bf16 GEMM: C[b] = A[b] @ W[sid[b]]^T + bias[sid[b]]  (opt. ReLU)
// (unchanged from previous round)
// ---------------------------------------------------------------------------
__global__ __launch_bounds__(256) void mfma_gemm(
    const float* __restrict__ A1, long long sA1,
    const float* __restrict__ A2, long long sA2, int splitM, int lda,
    const float* __restrict__ W, long long sW, int ldw,
    const float* __restrict__ bias, long long sB,
    float* __restrict__ C, long long sC, int ldc,
    const int* __restrict__ sid, int M, int N, int K, int tilesM, int relu)
{
    __shared__ unsigned short As[128][88];
    __shared__ unsigned short Bs[128][88];

    int b = blockIdx.z;
    int s = sid[b];
    int ty = blockIdx.x % tilesM;
    int tx = blockIdx.x / tilesM;
    int tm0 = ty * 128, tn0 = tx * 128;

    const float* Wb = W + (long long)s * sW;
    const float* Bb = bias + (long long)s * sB;
    float* Cb = C + (long long)b * sC;

    int t = threadIdx.x;
    int lane = t & 63, wv = t >> 6;
    int wm = wv >> 1, wn = wv & 1;
    int q = lane >> 4, mrow = lane & 15;

    floatx4 acc[4][4] = {};

    for (int k0 = 0; k0 < K; k0 += 64) {
        #pragma unroll
        for (int p = 0; p < 8; p++) {
            int row = (t >> 4) + 16 * p;
            int kf  = (t & 15) * 4;
            int ar = tm0 + row;
            float4 v = make_float4(0.f, 0.f, 0.f, 0.f);
            if (ar < M) {
                const float* src = (ar < splitM)
                    ? (A1 + (long long)b * sA1 + (long long)ar * lda)
                    : (A2 + (long long)b * sA2 + (long long)(ar - splitM) * lda);
                v = *(const float4*)(src + k0 + kf);
            }
            *(uint2*)&As[row][kf] = make_uint2(pkbf(v.x, v.y), pkbf(v.z, v.w));
        }
        #pragma unroll
        for (int p = 0; p < 8; p++) {
            int row = (t >> 4) + 16 * p;
            int kf  = (t & 15) * 4;
            const float* src = Wb + (long long)(tn0 + row) * ldw + k0 + kf;
            float4 v = *(const float4*)src;
            *(uint2*)&Bs[row][kf] = make_uint2(pkbf(v.x, v.y), pkbf(v.z, v.w));
        }
        __syncthreads();

        #pragma unroll
        for (int ks = 0; ks < 2; ks++) {
            int kk = ks * 32 + q * 8;
            short8 af[4], bfr[4];
            #pragma unroll
            for (int i = 0; i < 4; i++) {
                af[i]  = *(const short8*)&As[wm * 64 + i * 16 + mrow][kk];
                bfr[i] = *(const short8*)&Bs[wn * 64 + i * 16 + mrow][kk];
            }
            #pragma unroll
            for (int mi = 0; mi < 4; mi++)
                #pragma unroll
                for (int ni = 0; ni < 4; ni++)
                    acc[mi][ni] = __builtin_amdgcn_mfma_f32_16x16x32_bf16(
                        af[mi], bfr[ni], acc[mi][ni], 0, 0, 0);
        }
        __syncthreads();
    }

    #pragma unroll
    for (int ni = 0; ni < 4; ni++) {
        int cgl = tn0 + wn * 64 + ni * 16 + mrow;
        float bv = Bb[cgl];
        #pragma unroll
        for (int mi = 0; mi < 4; mi++) {
            #pragma unroll
            for (int e = 0; e < 4; e++) {
                int r = tm0 + wm * 64 + mi * 16 + q * 4 + e;
                if (r < M) {
                    float o = acc[mi][ni][e] + bv;
                    if (relu) o = fmaxf(o, 0.f);
                    Cb[(long long)r * ldc + cgl] = o;
                }
            }
        }
    }
}

// ---------------------------------------------------------------------------
// MFMA attention: block per (b, h, 32-q-row tile). 256 thr = 4 waves.
// KV tiles of 64; wave w owns j-slice [16w,16w+16) per tile.
//   S^T = K_slice . Q^T  : 2x mfma_f32_16x16x32_bf16 (K=32=DH, Q B-frags
//     hoisted). C layout: col=lane&15=q(+16nt), row=4*quad+e=j-local.
//   per-wave ONLINE softmax over its slice (in-lane e-reduce + shfl_xor
//     16/32 over the quad bits); no cross-wave sync per tile.
//   P^T packs straight into the B-operand of one mfma_f32_32x32x16_bf16
//     (K=16=slice) via per-wave LDS round-trip (4xb32 wr + 1xb128 rd,
//     XOR-16 swizzled).  O^T = V^T . P^T;  V staged transposed bf16.
//   end: single 4-wave merge (exact flash-merge) via LDS union.
// K/V prefetched to regs (T14): 2 barriers/tile.  LDS 19456 B -> 8 blk/CU.
// ---------------------------------------------------------------------------
__global__ __launch_bounds__(256) void attn3(
    const float* __restrict__ Q, long long sQ, int ldq,
    const float* __restrict__ Kp, long long sK, int ldk,
    const float* __restrict__ Vp, long long sV, int ldv,
    const unsigned char* __restrict__ m1, int sM1,
    const unsigned char* __restrict__ m2, int sM2,
    int split, int nk, int ntiles,
    float* __restrict__ O, long long sO, int ldo, float scale)
{
    __shared__ __align__(16) char smem[19456];
    unsigned short (*Kl)[40] = (unsigned short (*)[40])(smem);          //  [64][40]
    unsigned short (*Vt)[36] = (unsigned short (*)[36])(smem + 5120);   //  [32][36]
    unsigned short (*Ql)[40] = (unsigned short (*)[40])(smem + 7424);   //  [32][40]
    char* Pbyte = smem + 9984;                                          //  4x[32][24]
    float* mkf  = (float*)(smem + 16128);                               //  [64]

    int t = threadIdx.x;
    int qt = blockIdx.x, h = blockIdx.y, b = blockIdx.z;
    int qbase = qt * 32;

    const float* Qb = Q  + (long long)b * sQ + h * kDH;
    const float* Kb = Kp + (long long)b * sK + h * kDH;
    const float* Vb = Vp + (long long)b * sV + h * kDH;

    int lane = t & 63, w = t >> 6;
    int lq = lane & 15, q4 = lane >> 4;       // 16x16 roles
    int d31 = lane & 31, hh = lane >> 5;      // 32x32 roles
    int sj = t >> 2, sd = (t & 3) * 8;        // staging roles

    // ---- stage Q (once): 32x32 bf16 ----
    {
        int q = t >> 3, df = (t & 7) * 4;
        int gq = qbase + q;
        float4 v = make_float4(0.f, 0.f, 0.f, 0.f);
        if (gq < kT) v = *(const float4*)(Qb + (long long)gq * ldq + df);
        *(uint2*)&Ql[q][df] = make_uint2(pkbf(v.x, v.y), pkbf(v.z, v.w));
    }

    float4 ka, kb, va, vb; float mkv = 0.f;
    auto issue_loads = [&](int jt) {
        int gj = jt + sj;
        if (gj < nk) {
            const float* kp = Kb + (long long)gj * ldk + sd;
            const float* vp = Vb + (long long)gj * ldv + sd;
            ka = *(const float4*)kp;  kb = *(const float4*)(kp + 4);
            va = *(const float4*)vp;  vb = *(const float4*)(vp + 4);
        } else {
            ka = kb = va = vb = make_float4(0.f, 0.f, 0.f, 0.f);
        }
        if (t < 64) {
            int tj = jt + t;
            if (tj < nk)
                mkv = ((tj < split) ? m1[b * sM1 + tj] : m2[b * sM2 + (tj - split)])
                        ? kNEG : 0.f;
            else
                mkv = -INFINITY;
        }
    };
    auto write_stage = [&]() {
        *(uint4*)&Kl[sj][sd] = make_uint4(pkbf(ka.x, ka.y), pkbf(ka.z, ka.w),
                                          pkbf(kb.x, kb.y), pkbf(kb.z, kb.w));
        Vt[sd + 0][sj] = bf16u(va.x); Vt[sd + 1][sj] = bf16u(va.y);
        Vt[sd + 2][sj] = bf16u(va.z); Vt[sd + 3][sj] = bf16u(va.w);
        Vt[sd + 4][sj] = bf16u(vb.x); Vt[sd + 5][sj] = bf16u(vb.y);
        Vt[sd + 6][sj] = bf16u(vb.z); Vt[sd + 7][sj] = bf16u(vb.w);
        if (t < 64) mkf[t] = mkv;
    };

    issue_loads(0);
    write_stage();
    __syncthreads();

    // Hoisted Q B-frags (loop-invariant)
    short8 Bq0 = *(const short8*)&Ql[lq][8 * q4];
    short8 Bq1 = *(const short8*)&Ql[lq + 16][8 * q4];

    floatx16 accO = {};
    float m0 = -INFINITY, m1v = -INFINITY, l0 = 0.f, l1 = 0.f;
    char* Pw = Pbyte + w * 1536;

    for (int tile = 0; tile < ntiles; tile++) {
        bool pf = (tile + 1 < ntiles);
        if (pf) issue_loads((tile + 1) * 64);

        // ---- S^T = K_slice . Q^T ----
        short8 akf = *(const short8*)&Kl[16 * w + lq][8 * q4];
        floatx4 c0 = {}, c1 = {};
        c0 = __builtin_amdgcn_mfma_f32_16x16x32_bf16(akf, Bq0, c0, 0, 0, 0);
        c1 = __builtin_amdgcn_mfma_f32_16x16x32_bf16(akf, Bq1, c1, 0, 0, 0);

        float mka0 = mkf[16 * w + 4 * q4 + 0];
        float mka1 = mkf[16 * w + 4 * q4 + 1];
        float mka2 = mkf[16 * w + 4 * q4 + 2];
        float mka3 = mkf[16 * w + 4 * q4 + 3];

        float s00 = c0[0] * scale + mka0, s01 = c0[1] * scale + mka1;
        float s02 = c0[2] * scale + mka2, s03 = c0[3] * scale + mka3;
        float s10 = c1[0] * scale + mka0, s11 = c1[1] * scale + mka1;
        float s12 = c1[2] * scale + mka2, s13 = c1[3] * scale + mka3;

        // per-wave online softmax over the 16-j slice
        float mt0 = fmaxf(fmaxf(s00, s01), fmaxf(s02, s03));
        float mt1 = fmaxf(fmaxf(s10, s11), fmaxf(s12, s13));
        mt0 = fmaxf(mt0, __shfl_xor(mt0, 16)); mt0 = fmaxf(mt0, __shfl_xor(mt0, 32));
        mt1 = fmaxf(mt1, __shfl_xor(mt1, 16)); mt1 = fmaxf(mt1, __shfl_xor(mt1, 32));
        float mn0 = fmaxf(m0, mt0), mn1 = fmaxf(m1v, mt1);
        float al0 = __expf(m0 - mn0), al1 = __expf(m1v - mn1);

        float p00 = __expf(s00 - mn0), p01 = __expf(s01 - mn0);
        float p02 = __expf(s02 - mn0), p03 = __expf(s03 - mn0);
        float p10 = __expf(s10 - mn1), p11 = __expf(s11 - mn1);
        float p12 = __expf(s12 - mn1), p13 = __expf(s13 - mn1);

        float sum0 = (p00 + p01) + (p02 + p03);
        float sum1 = (p10 + p11) + (p12 + p13);
        sum0 += __shfl_xor(sum0, 16); sum0 += __shfl_xor(sum0, 32);
        sum1 += __shfl_xor(sum1, 16); sum1 += __shfl_xor(sum1, 32);
        l0 = l0 * al0 + sum0;  l1 = l1 * al1 + sum1;
        m0 = mn0;  m1v = mn1;

        // ---- P^T round-trip (per-wave buffer, XOR-16 swizzle on 16B blk) ----
        *(unsigned*)(Pw + lq * 48 + (8 * q4 + 0))        = pkbf(p00, p01);
        *(unsigned*)(Pw + lq * 48 + (8 * q4 + 4))        = pkbf(p02, p03);
        *(unsigned*)(Pw + (lq + 16) * 48 + ((8 * q4 + 0) ^ 16)) = pkbf(p10, p11);
        *(unsigned*)(Pw + (lq + 16) * 48 + ((8 * q4 + 4) ^ 16)) = pkbf(p12, p13);
        short8 bp = *(const short8*)(Pw + d31 * 48 + ((16 * hh) ^ (d31 & 16)));

        // ---- V^T A-frag: 2 x b64 from Vt[d][16w+8hh ..] ----
        int j0 = 16 * w + 8 * hh;
        uint2 va2 = *(const uint2*)&Vt[d31][j0];
        uint2 vb2 = *(const uint2*)&Vt[d31][j0 + 4];
        union { unsigned u[4]; short8 s; } avu;
        avu.u[0] = va2.x; avu.u[1] = va2.y; avu.u[2] = vb2.x; avu.u[3] = vb2.y;

        // ---- O^T rescale + accumulate ----
        float als = (lane & 16) ? al1 : al0;   // alpha of q = lane&31
        #pragma unroll
        for (int e = 0; e < 16; e++) accO[e] *= als;
        accO = __builtin_amdgcn_mfma_f32_32x32x16_bf16(avu.s, bp, accO, 0, 0, 0);

        __syncthreads();
        if (pf) { write_stage(); __syncthreads(); }
    }

    // ---- merge 4 waves (exact): reuse smem as Ow[4][32 q][36 d] + stats ----
    float* Ow = (float*)smem;
    float* ms = (float*)(smem + 18432);   // [4][32]
    float* ls = (float*)(smem + 18944);   // [4][32]
    #pragma unroll
    for (int g = 0; g < 4; g++) {
        int d0 = 8 * g + 4 * hh;          // C row = (e&3) + 8*(e>>2) + 4*hh
        float4 ve = make_float4(accO[4 * g + 0], accO[4 * g + 1],
                                accO[4 * g + 2], accO[4 * g + 3]);
        *(float4*)&Ow[(w * 32 + d31) * 36 + d0] = ve;
    }
    if (q4 == 0) {
        ms[w * 32 + lq] = m0;   ms[w * 32 + lq + 16] = m1v;
        ls[w * 32 + lq] = l0;   ls[w * 32 + lq + 16] = l1;
    }
    __syncthreads();
    {
        int qq = t >> 3, db = (t & 7) * 4;
        float mw0 = ms[qq],      mw1 = ms[32 + qq];
        float mw2 = ms[64 + qq], mw3 = ms[96 + qq];
        float M = fmaxf(fmaxf(mw0, mw1), fmaxf(mw2, mw3));
        float e0 = __expf(mw0 - M), e1 = __expf(mw1 - M);
        float e2 = __expf(mw2 - M), e3 = __expf(mw3 - M);
        float L = e0 * ls[qq] + e1 * ls[32 + qq] + e2 * ls[64 + qq] + e3 * ls[96 + qq];
        float inv = 1.f / L;
        float4 o0 = *(const float4*)&Ow[(0 * 32 + qq) * 36 + db];
        float4 o1 = *(const float4*)&Ow[(1 * 32 + qq) * 36 + db];
        float4 o2 = *(const float4*)&Ow[(2 * 32 + qq) * 36 + db];
        float4 o3 = *(const float4*)&Ow[(3 * 32 + qq) * 36 + db];
        float4 o;
        o.x = (e0 * o0.x + e1 * o1.x + e2 * o2.x + e3 * o3.x) * inv;
        o.y = (e0 * o0.y + e1 * o1.y + e2 * o2.y + e3 * o3.y) * inv;
        o.z = (e0 * o0.z + e1 * o1.z + e2 * o2.z + e3 * o3.z) * inv;
        o.w = (e0 * o0.w + e1 * o1.w + e2 * o2.w + e3 * o3.w) * inv;
        int gq = qbase + qq;
        if (gq < kT)
            *(float4*)(O + (long long)b * sO + (long long)gq * ldo + h * kDH + db) = o;
    }
}

// ---------------------------------------------------------------------------
// Fused residual-add + LayerNorm over D=256. Block = 256 threads = one row.
// ---------------------------------------------------------------------------
__global__ __launch_bounds__(256) void addln_kernel(
    const float* __restrict__ A, const float* __restrict__ R,
    const float* __restrict__ w, const float* __restrict__ bb,
    const int* __restrict__ sid, float* __restrict__ O)
{
    int t = blockIdx.x, b = blockIdx.y, d = threadIdx.x;
    long long base = ((long long)(b * kT + t)) * kD;
    float x = A[base + d] + R[base + d];

    __shared__ float r1[4], r2[4];
    int wid = d >> 6;

    float sacc = x;
    #pragma unroll
    for (int off = 32; off >= 1; off >>= 1) sacc += __shfl_xor(sacc, off);
    if ((d & 63) == 0) r1[wid] = sacc;
    __syncthreads();
    float mean = (r1[0] + r1[1] + r1[2] + r1[3]) * (1.0f / 256.0f);

    float diff = x - mean;
    float s2 = diff * diff;
    #pragma unroll
    for (int off = 32; off >= 1; off >>= 1) s2 += __shfl_xor(s2, off);
    if ((d & 63) == 0) r2[wid] = s2;
    __syncthreads();
    float var = (r2[0] + r2[1] + r2[2] + r2[3]) * (1.0f / 256.0f);

    int s = sid[b];
    float y = diff * rsqrtf(var + kEPS) * w[s * kD + d] + bb[s * kD + d];
    O[base + d] = y;
}

// ---------------------------------------------------------------------------
// Launch
// ---------------------------------------------------------------------------
extern "C" void kernel_launch(void* const* d_in, const int* in_sizes, int n_in,
                              void* d_out, int out_size, void* d_ws, size_t ws_size,
                              hipStream_t stream)
{
    const float*         text   = (const float*)d_in[0];
    const unsigned char* tmask  = (const unsigned char*)d_in[1];
    const float*         im1    = (const float*)d_in[2];
    const unsigned char* immk1  = (const unsigned char*)d_in[3];
    const float*         im2    = (const float*)d_in[4];
    const unsigned char* immk2  = (const unsigned char*)d_in[5];
    const int*           sid    = (const int*)d_in[6];
    const float* sa_in_w  = (const float*)d_in[7];
    const float* sa_in_b  = (const float*)d_in[8];
    const float* sa_out_w = (const float*)d_in[9];
    const float* sa_out_b = (const float*)d_in[10];
    const float* ca_in_w  = (const float*)d_in[11];
    const float* ca_in_b  = (const float*)d_in[12];
    const float* ca_out_w = (const float*)d_in[13];
    const float* ca_out_b = (const float*)d_in[14];
    const float* lin1_w   = (const float*)d_in[15];
    const float* lin1_b   = (const float*)d_in[16];
    const float* lin2_w   = (const float*)d_in[17];
    const float* lin2_b   = (const float*)d_in[18];
    const float* ln1_w    = (const float*)d_in[19];
    const float* ln1_b    = (const float*)d_in[20];
    const float* ln2_w    = (const float*)d_in[21];
    const float* ln2_b    = (const float*)d_in[22];
    const float* ln3_w    = (const float*)d_in[23];
    const float* ln3_b    = (const float*)d_in[24];
    float* out = (float*)d_out;

    // Workspace layout (floats)
    float* ws = (float*)d_ws;
    float* qkv_sa  = ws;                                   // B*T*768
    float* q_ca    = qkv_sa  + (long long)kB * kT * 768;   // B*T*256
    float* kv_ca   = q_ca    + (long long)kB * kT * kD;    // B*800*512
    float* attnbuf = kv_ca   + (long long)kB * kMKV * 512; // B*T*256
    float* tmp     = attnbuf + (long long)kB * kT * kD;    // B*T*256
    float* x1      = tmp     + (long long)kB * kT * kD;    // B*T*256
    float* x2      = x1      + (long long)kB * kT * kD;    // B*T*256
    float* hff     = x2      + (long long)kB * kT * kD;    // B*T*2048

    const float scale = 0.17677669529663687f;  // 1/sqrt(32)
    dim3 blk(256);

    auto gemm = [&](const float* A1, long long sA1, const float* A2, long long sA2,
                    int splitM, int lda,
                    const float* W, long long sW, int ldw,
                    const float* bias, long long sB,
                    float* C, long long sC, int ldc,
                    int M, int N, int K, int relu) {
        int tm = (M + 127) / 128, tn = N / 128;
        mfma_gemm<<<dim3(tm * tn, 1, kB), blk, 0, stream>>>(
            A1, sA1, A2, sA2, splitM, lda, W, sW, ldw, bias, sB,
            C, sC, ldc, sid, M, N, K, tm, relu);
    };

    // 1. SA QKV: (B,77,768)
    gemm(text, (long long)kT * kD, text, 0, kT, kD,
         sa_in_w, (long long)3 * kD * kD, kD, sa_in_b, 3 * kD,
         qkv_sa, (long long)kT * 768, 768, kT, 768, kD, 0);

    // 2. SA attention -> attnbuf
    attn3<<<dim3(3, kH, kB), blk, 0, stream>>>(
        qkv_sa,       (long long)kT * 768, 768,
        qkv_sa + 256, (long long)kT * 768, 768,
        qkv_sa + 512, (long long)kT * 768, 768,
        tmask, kT, tmask, kT, kT, kT, 2,
        attnbuf, (long long)kT * kD, kD, scale);

    // 3. SA out-proj -> tmp
    gemm(attnbuf, (long long)kT * kD, attnbuf, 0, kT, kD,
         sa_out_w, (long long)kD * kD, kD, sa_out_b, kD,
         tmp, (long long)kT * kD, kD, kT, kD, kD, 0);

    // 4. x1 = LN1(tmp + text)
    addln_kernel<<<dim3(kT, kB), blk, 0, stream>>>(tmp, text, ln1_w, ln1_b, sid, x1);

    // 5. CA Q (rows 0..255 of ca_in_w)
    gemm(x1, (long long)kT * kD, x1, 0, kT, kD,
         ca_in_w, (long long)3 * kD * kD, kD, ca_in_b, 3 * kD,
         q_ca, (long long)kT * kD, kD, kT, kD, kD, 0);

    // 6. CA KV: concat(im1,im2) @ [wk;wv]^T -> kv_ca (B,800,512), single launch
    gemm(im1, (long long)kM1 * kD, im2, (long long)kM1 * kD, kM1, kD,
         ca_in_w + (long long)kD * kD, (long long)3 * kD * kD, kD,
         ca_in_b + kD, 3 * kD,
         kv_ca, (long long)kMKV * 512, 512, kMKV, 512, kD, 0);

    // 7. CA attention -> attnbuf
    attn3<<<dim3(3, kH, kB), blk, 0, stream>>>(
        q_ca,        (long long)kT * kD, kD,
        kv_ca,       (long long)kMKV * 512, 512,
        kv_ca + 256, (long long)kMKV * 512, 512,
        immk1, kM1, immk2, kM1, kM1, kMKV, 13,
        attnbuf, (long long)kT * kD, kD, scale);

    // 8. CA out-proj -> tmp
    gemm(attnbuf, (long long)kT * kD, attnbuf, 0, kT, kD,
         ca_out_w, (long long)kD * kD, kD, ca_out_b, kD,
         tmp, (long long)kT * kD, kD, kT, kD, kD, 0);

    // 9. x2 = LN2(tmp + x1)
    addln_kernel<<<dim3(kT, kB), blk, 0, stream>>>(tmp, x1, ln2_w, ln2_b, sid, x2);

    // 10. FFN1: hff = relu(x2 @ lin1_w^T + lin1_b)
    gemm(x2, (long long)kT * kD, x2, 0, kT, kD,
         lin1_w, (long long)kDFF * kD, kD, lin1_b, kDFF,
         hff, (long long)kT * kDFF, kDFF, kT, kDFF, kD, 1);

    // 11. FFN2: tmp = hff @ lin2_w^T + lin2_b
    gemm(hff, (long long)kT * kDFF, hff, 0, kT, kDFF,
         lin2_w, (long long)kD * kDFF, kDFF, lin2_b, kD,
         tmp, (long long)kT * kD, kD, kT, kD, kDFF, 0);

    // 12. out = LN3(tmp + x2)
    addln_kernel<<<dim3(kT, kB), blk, 0, stream>>>(tmp, x2, ln3_w, ln3_b, sid, out);
}